// Round 13
// baseline (364.675 us; speedup 1.0000x reference)
//
#include <hip/hip_runtime.h>

#define T_STEPS 100
#define BATCH   512
#define FIN     784
#define O1      100
#define O2      10

typedef __attribute__((ext_vector_type(4))) double f64x4;

// ---------------------------------------------------------------------------
// K1 v11: fused C-mean + f64 MFMA GEMM — NO LDS, NO BARRIERS.
//   I1T[t][o][b] = sum_f 0.5*(in[b,t,f,0]+in[b,t,f,1]) * W1[f,o]
// Rounds 4-12 all capped at MfmaUtil 38-52%: the 2-barrier-per-chunk lockstep
// makes every wave pay every per-chunk latency. v11: each wave is fully
// independent — it owns 16 b-rows x ALL 7 o-tiles for one t, reads its
// B-fragments straight from global (16 rows, 32B/quad, line-sequential per
// row -> input fetched exactly once; 128B line serves 4 consecutive quads),
// W from registers (f32, L1-hot: all 4 waves of a block read identical
// addresses). Explicit ping-pong pipeline, all-static register arrays:
//   per half-chunk: 49 W loads (older) -> 7 B loads for NEXT chunk (younger)
//   -> 49 MFMAs (counted vmcnt waits W only; B prefetch stays in flight
//   ~790 cy until its compute). Waves desync freely; no drain points.
// o-tiles {0,16,32,48,64,80,84}; tile 84 overlaps 80 -> duplicate stores
// bitwise identical. Grid (8,100) = 800 blocks x 4 waves.
// ---------------------------------------------------------------------------
__global__ __launch_bounds__(256) void k1_mfma(const float* __restrict__ in,
                                               const float* __restrict__ W1,
                                               double* __restrict__ I1T) {
  const int tid = threadIdx.x;
  const int l   = tid & 63;
  const int w   = tid >> 6;
  const int r16 = l & 15;
  const int q16 = l >> 4;
  const int b0  = (int)blockIdx.x * 64 + w * 16;  // wave's 16-row group
  const int t   = (int)blockIdx.y;

  // --- in-kernel D-layout probe (validated rounds 3-12) ---
  const f64x4 z = {0.0, 0.0, 0.0, 0.0};
  f64x4 pr = __builtin_amdgcn_mfma_f64_16x16x4f64((double)r16, 0.25, z, 0, 0, 0);
  f64x4 pc = __builtin_amdgcn_mfma_f64_16x16x4f64(0.25, (double)r16, z, 0, 0, 0);
  int soff0, soff1, soff2, soff3;
  {
    int rm0 = (int)(pr[0] + 0.5), cm0 = (int)(pc[0] + 0.5);
    int rm1 = (int)(pr[1] + 0.5), cm1 = (int)(pc[1] + 0.5);
    int rm2 = (int)(pr[2] + 0.5), cm2 = (int)(pc[2] + 0.5);
    int rm3 = (int)(pr[3] + 0.5), cm3 = (int)(pc[3] + 0.5);
    soff0 = rm0 * BATCH + cm0; soff1 = rm1 * BATCH + cm1;
    soff2 = rm2 * BATCH + cm2; soff3 = rm3 * BATCH + cm3;
  }

  // B source: lane reads float2 (both channels) of row b0+r16 at f = 4*kq+q16
  const float2* pB = reinterpret_cast<const float2*>(in) +
                     ((size_t)(b0 + r16) * T_STEPS + t) * FIN + q16;
  // W source: lane reads W1[(4*kq+q16)*100 + o_n + r16]
  const float* pW = W1 + (size_t)q16 * O1 + r16;

  f64x4 A0 = z, A1 = z, A2 = z, A3 = z, A4 = z, A5 = z, A6 = z;

  float2 Bp[7], Bn[7];
#pragma unroll
  for (int q = 0; q < 7; ++q) Bp[q] = pB[4 * q];   // chunk 0

#define MF(D, Aop, Bop) D = __builtin_amdgcn_mfma_f64_16x16x4f64((Aop), (Bop), (D), 0, 0, 0)
#define LOADW(DST, C)                                                     \
  _Pragma("unroll")                                                       \
  for (int q = 0; q < 7; ++q) {                                           \
    const float* pw = pW + (size_t)((C) * 7 + q) * 400;                   \
    DST[q][0] = pw[0];  DST[q][1] = pw[16]; DST[q][2] = pw[32];           \
    DST[q][3] = pw[48]; DST[q][4] = pw[64]; DST[q][5] = pw[80];           \
    DST[q][6] = pw[84];                                                   \
  }
#define COMPUTE(BS, WS)                                                   \
  _Pragma("unroll")                                                       \
  for (int q = 0; q < 7; ++q) {                                           \
    const double bv = 0.5 * ((double)BS[q].x + (double)BS[q].y);          \
    MF(A0, (double)WS[q][0], bv); MF(A1, (double)WS[q][1], bv);           \
    MF(A2, (double)WS[q][2], bv); MF(A3, (double)WS[q][3], bv);           \
    MF(A4, (double)WS[q][4], bv); MF(A5, (double)WS[q][5], bv);           \
    MF(A6, (double)WS[q][6], bv);                                         \
  }

  for (int cc = 0; cc < 14; ++cc) {        // 2 chunks per iteration
    const int c0 = 2 * cc, c1 = c0 + 1;
    // half 1: W(c0) first (older), B(c1) prefetch (younger), compute c0
    float Wa[7][7];
    LOADW(Wa, c0);
#pragma unroll
    for (int q = 0; q < 7; ++q) Bn[q] = pB[(c1 * 7 + q) * 4];
    COMPUTE(Bp, Wa);
    // half 2: W(c1), B(c0+2) prefetch, compute c1
    float Wb[7][7];
    LOADW(Wb, c1);
    if (cc < 13) {
#pragma unroll
      for (int q = 0; q < 7; ++q) Bp[q] = pB[((c0 + 2) * 7 + q) * 4];
    }
    COMPUTE(Bn, Wb);
  }
#undef COMPUTE
#undef LOADW
#undef MF

  // epilogue: 7 static tile stores through the probed D map
  double* base = I1T + ((size_t)t * O1) * BATCH + b0;
#define ST(ACC, O0)                                                        \
  {                                                                        \
    base[(size_t)(O0) * BATCH + soff0] = (ACC)[0];                         \
    base[(size_t)(O0) * BATCH + soff1] = (ACC)[1];                         \
    base[(size_t)(O0) * BATCH + soff2] = (ACC)[2];                         \
    base[(size_t)(O0) * BATCH + soff3] = (ACC)[3];                         \
  }
  ST(A0, 0); ST(A1, 16); ST(A2, 32); ST(A3, 48);
  ST(A4, 64); ST(A5, 80); ST(A6, 84);
#undef ST
}

// ---------------------------------------------------------------------------
// K2: BN stats per (t,o) row: mu, rstd. One wave per row.
// ---------------------------------------------------------------------------
__global__ __launch_bounds__(256) void k2_bnstats(const double* __restrict__ I1T,
                                                  double* __restrict__ mu,
                                                  double* __restrict__ rstd) {
  const int r    = blockIdx.x * 4 + (threadIdx.x >> 6);
  const int lane = threadIdx.x & 63;
  const double2* row2 = reinterpret_cast<const double2*>(I1T + (size_t)r * BATCH) + lane * 4;
  double v[8];
#pragma unroll
  for (int u = 0; u < 4; ++u) {
    double2 p = row2[u];
    v[2 * u] = p.x; v[2 * u + 1] = p.y;
  }
  double s = 0.0;
#pragma unroll
  for (int u = 0; u < 8; ++u) s += v[u];
#pragma unroll
  for (int m = 32; m >= 1; m >>= 1) s += __shfl_xor(s, m, 64);
  const double mean = s / 512.0;
  double q = 0.0;
#pragma unroll
  for (int u = 0; u < 8; ++u) { double d = v[u] - mean; q += d * d; }
#pragma unroll
  for (int m = 32; m >= 1; m >>= 1) q += __shfl_xor(q, m, 64);
  if (lane == 0) {
    mu[r]   = mean;
    rstd[r] = 1.0 / sqrt(q / 512.0 + 1e-5);
  }
}

// ---------------------------------------------------------------------------
// K3: layer-1 LIF scan. Block = o, thread = b.
// ---------------------------------------------------------------------------
__global__ __launch_bounds__(512) void k3_lif1(const double* __restrict__ I1T,
                                               const double* __restrict__ mu,
                                               const double* __restrict__ rstd,
                                               const float* __restrict__ scale,
                                               const float* __restrict__ bias,
                                               float* __restrict__ z1T) {
  const int o = blockIdx.x;
  const int b = threadIdx.x;
  const double sc = (double)scale[o], bs = (double)bias[o];
  double v = 0.0;
  for (int tc = 0; tc < T_STEPS; tc += 10) {
    double x[10], muv[10], rsv[10];
#pragma unroll
    for (int u = 0; u < 10; ++u) {
      const int t = tc + u;
      x[u]   = I1T[((size_t)t * O1 + o) * BATCH + b];
      muv[u] = mu[t * O1 + o];
      rsv[u] = rstd[t * O1 + o];
    }
#pragma unroll
    for (int u = 0; u < 10; ++u) {
      const double i = ((x[u] - muv[u]) * rsv[u]) * sc + bs;
      v = 0.95 * v + i;
      const bool z = (v > 1.0);
      z1T[((size_t)(tc + u) * O1 + o) * BATCH + b] = z ? 1.0f : 0.0f;
      if (z) v = 0.0;
    }
  }
}

// ---------------------------------------------------------------------------
// K4: I2[t][j][b] = sum_o z1T[t][o][b] * W2[o][j].
// ---------------------------------------------------------------------------
__global__ __launch_bounds__(512) void k4_proj2(const float* __restrict__ z1T,
                                                const float* __restrict__ W2,
                                                double* __restrict__ I2) {
  __shared__ double W2_lds[O1 * O2];
  const int t = blockIdx.x;
  const int b = threadIdx.x;
  for (int i = threadIdx.x; i < O1 * O2; i += 512) W2_lds[i] = (double)W2[i];
  __syncthreads();
  double acc[O2];
#pragma unroll
  for (int j = 0; j < O2; ++j) acc[j] = 0.0;
  for (int o = 0; o < O1; ++o) {
    const double z = (double)z1T[((size_t)t * O1 + o) * BATCH + b];
#pragma unroll
    for (int j = 0; j < O2; ++j) acc[j] += z * W2_lds[o * O2 + j];
  }
#pragma unroll
  for (int j = 0; j < O2; ++j)
    I2[((size_t)t * O2 + j) * BATCH + b] = acc[j];
}

// ---------------------------------------------------------------------------
// K5: layer-2 LIF scan + time-mean.
// ---------------------------------------------------------------------------
__global__ __launch_bounds__(512) void k5_lif2(const double* __restrict__ I2,
                                               float* __restrict__ out) {
  const int j = blockIdx.x;
  const int b = threadIdx.x;
  double v = 0.0;
  int cnt = 0;
  for (int tc = 0; tc < T_STEPS; tc += 10) {
    double x[10];
#pragma unroll
    for (int u = 0; u < 10; ++u)
      x[u] = I2[((size_t)(tc + u) * O2 + j) * BATCH + b];
#pragma unroll
    for (int u = 0; u < 10; ++u) {
      v = 0.95 * v + x[u];
      if (v > 1.0) { ++cnt; v = 0.0; }
    }
  }
  out[b * O2 + j] = (float)((double)cnt / 100.0);
}

// ---------------------------------------------------------------------------
extern "C" void kernel_launch(void* const* d_in, const int* in_sizes, int n_in,
                              void* d_out, int out_size, void* d_ws, size_t ws_size,
                              hipStream_t stream) {
  const float* in    = (const float*)d_in[0];
  const float* W1    = (const float*)d_in[2];
  const float* scale = (const float*)d_in[3];
  const float* bias  = (const float*)d_in[4];
  const float* W2    = (const float*)d_in[5];
  float* out = (float*)d_out;

  char* ws = (char*)d_ws;
  size_t off = 0;
  double* I1T  = (double*)(ws + off); off += (size_t)T_STEPS * O1 * BATCH * sizeof(double);
  double* mu   = (double*)(ws + off); off += (size_t)T_STEPS * O1 * sizeof(double);
  double* rstd = (double*)(ws + off); off += (size_t)T_STEPS * O1 * sizeof(double);
  float*  z1T  = (float*)(ws + off);  off += (size_t)T_STEPS * O1 * BATCH * sizeof(float);
  double* I2   = (double*)(ws + off); off += (size_t)T_STEPS * O2 * BATCH * sizeof(double);

  k1_mfma   <<<dim3(BATCH / 64, T_STEPS), 256, 0, stream>>>(in, W1, I1T);
  k2_bnstats<<<dim3(T_STEPS * O1 / 4), 256, 0, stream>>>(I1T, mu, rstd);
  k3_lif1   <<<dim3(O1), 512, 0, stream>>>(I1T, mu, rstd, scale, bias, z1T);
  k4_proj2  <<<dim3(T_STEPS), 512, 0, stream>>>(z1T, W2, I2);
  k5_lif2   <<<dim3(O2), 512, 0, stream>>>(I2, out);
}

// Round 14
// 273.235 us; speedup vs baseline: 1.3347x; 1.3347x over previous
//
#include <hip/hip_runtime.h>

#define T_STEPS 100
#define BATCH   512
#define FIN     784
#define O1      100
#define O2      10
#define NC1     28      // 28 chunks of K=28

typedef __attribute__((ext_vector_type(4))) double f64x4;

// ---------------------------------------------------------------------------
// K1 v13: fused C-mean + f64 MFMA GEMM — barrier-free, per-wave LDS transpose.
//   I1T[t][o][b] = sum_f 0.5*(in[b,t,f,0]+in[b,t,f,1]) * W1[f,o]
// Each wave owns 16 b-rows x ALL 7 o-tiles for one t and stages ITS OWN
// B-tile through a private LDS slice (pure lane-transpose: coalesced float4
// staging -> MFMA fragment layout). No cross-wave sharing -> NO barriers;
// own-wave LDS RAW is ordered by the compiler's lgkmcnt. W in registers
// (f32, L1-hot), single generation, issued at the end of compute(c) so it
// reuses the same regs and lands during ds_write+lgkm of c+1.
// vmcnt queue: [ist(c)] < [W(c)] < [ist(c+1)] < [W(c+1)] — ds_write waits
// only ist(c); compute waits only W(c); the HBM prefetch is never drained.
// o-tiles {0,16,32,48,64,80,84}; 84 overlaps 80 -> duplicate stores bitwise
// identical. Grid (8,100) = 800 blocks x 4 waves; ~145 regs -> 3 waves/SIMD.
// ---------------------------------------------------------------------------
__global__ __launch_bounds__(256) void k1_mfma(const float* __restrict__ in,
                                               const float* __restrict__ W1,
                                               double* __restrict__ I1T) {
  __shared__ double AI[2][4][NC1][17];   // [buf][wave][f-in-chunk][b-row] 30.6 KB
  const int tid = threadIdx.x;
  const int l   = tid & 63;
  const int w   = tid >> 6;
  const int r16 = l & 15;
  const int q16 = l >> 4;
  const int b0  = (int)blockIdx.x * 64 + w * 16;  // wave's 16-row group
  const int t   = (int)blockIdx.y;

  // --- staging descriptors: 224 float4 per wave (16 rows x 14) over 64 lanes
  bool iact[4]; int irow[4], iq[4]; const float* ibp[4];
#pragma unroll
  for (int p = 0; p < 4; ++p) {
    const int i = p * 64 + l;
    iact[p] = (i < 224);
    const int row = iact[p] ? i / 14 : 0;
    iq[p]   = (iact[p] ? i : 0) - row * 14;
    irow[p] = row;
    ibp[p]  = in + ((size_t)(b0 + row) * T_STEPS + t) * (FIN * 2) + iq[p] * 4;
  }

  // prologue: issue chunk-0 input loads (oldest in queue)
  float4 ist[4];
#pragma unroll
  for (int p = 0; p < 4; ++p) if (iact[p]) ist[p] = *reinterpret_cast<const float4*>(ibp[p]);

  // --- in-kernel D-layout probe (validated rounds 3-13) ---
  const f64x4 z = {0.0, 0.0, 0.0, 0.0};
  f64x4 pr = __builtin_amdgcn_mfma_f64_16x16x4f64((double)r16, 0.25, z, 0, 0, 0);
  f64x4 pc = __builtin_amdgcn_mfma_f64_16x16x4f64(0.25, (double)r16, z, 0, 0, 0);
  int soff0, soff1, soff2, soff3;
  {
    int rm0 = (int)(pr[0] + 0.5), cm0 = (int)(pc[0] + 0.5);
    int rm1 = (int)(pr[1] + 0.5), cm1 = (int)(pc[1] + 0.5);
    int rm2 = (int)(pr[2] + 0.5), cm2 = (int)(pc[2] + 0.5);
    int rm3 = (int)(pr[3] + 0.5), cm3 = (int)(pc[3] + 0.5);
    soff0 = rm0 * BATCH + cm0; soff1 = rm1 * BATCH + cm1;
    soff2 = rm2 * BATCH + cm2; soff3 = rm3 * BATCH + cm3;
  }

  // W source: lane (q16, r16) reads W1[(28c + 4q + q16)*100 + o_n + r16]
  const float* pW = W1 + (size_t)q16 * O1 + r16;

  f64x4 A0 = z, A1 = z, A2 = z, A3 = z, A4 = z, A5 = z, A6 = z;

  // prologue: issue W(0) (younger than ist(0))
  float wreg[7][7];
#pragma unroll
  for (int q = 0; q < 7; ++q) {
    const float* pw = pW + (size_t)q * 400;
    wreg[q][0] = pw[0];  wreg[q][1] = pw[16]; wreg[q][2] = pw[32];
    wreg[q][3] = pw[48]; wreg[q][4] = pw[64]; wreg[q][5] = pw[80];
    wreg[q][6] = pw[84];
  }

#define MF(D, Aop, Bop) D = __builtin_amdgcn_mfma_f64_16x16x4f64((Aop), (Bop), (D), 0, 0, 0)
  for (int c = 0; c < NC1; ++c) {
    const int buf = c & 1;
    // 1) ds_write chunk c from ist regs (waits vmcnt for ist(c) only — oldest;
    //    W(c) stays in flight). Exact f64 C-mean.
#pragma unroll
    for (int p = 0; p < 4; ++p)
      if (iact[p]) {
        AI[buf][w][iq[p] * 2 + 0][irow[p]] = 0.5 * ((double)ist[p].x + (double)ist[p].y);
        AI[buf][w][iq[p] * 2 + 1][irow[p]] = 0.5 * ((double)ist[p].z + (double)ist[p].w);
      }
    // 2) issue ist(c+1) (younger than W(c); survives the compute-phase W-wait,
    //    lands during the ~3136-cy MFMA burst)
    if (c + 1 < NC1) {
#pragma unroll
      for (int p = 0; p < 4; ++p)
        if (iact[p]) ist[p] = *reinterpret_cast<const float4*>(ibp[p] + (c + 1) * 56);
    }
    // 3) compute chunk c: own-wave lgkmcnt orders ds_write->ds_read; reading
    //    wreg waits vmcnt down to ist(c+1)'s count (W(c) retired, ist in flight)
#pragma unroll
    for (int q = 0; q < 7; ++q) {
      const double bv = AI[buf][w][q * 4 + q16][r16];
      MF(A0, (double)wreg[q][0], bv);
      MF(A1, (double)wreg[q][1], bv);
      MF(A2, (double)wreg[q][2], bv);
      MF(A3, (double)wreg[q][3], bv);
      MF(A4, (double)wreg[q][4], bv);
      MF(A5, (double)wreg[q][5], bv);
      MF(A6, (double)wreg[q][6], bv);
    }
    // 4) issue W(c+1) — same registers (live ranges don't overlap), has
    //    ds_write+lgkm of the next chunk to land (L1-hot)
    if (c + 1 < NC1) {
      const float* pWc = pW + (size_t)(c + 1) * (28 * O1);
#pragma unroll
      for (int q = 0; q < 7; ++q) {
        const float* pw = pWc + (size_t)q * 400;
        wreg[q][0] = pw[0];  wreg[q][1] = pw[16]; wreg[q][2] = pw[32];
        wreg[q][3] = pw[48]; wreg[q][4] = pw[64]; wreg[q][5] = pw[80];
        wreg[q][6] = pw[84];
      }
    }
  }
#undef MF

  // epilogue: 7 static tile stores through the probed D map
  double* base = I1T + ((size_t)t * O1) * BATCH + b0;
#define ST(ACC, O0)                                                        \
  {                                                                        \
    base[(size_t)(O0) * BATCH + soff0] = (ACC)[0];                         \
    base[(size_t)(O0) * BATCH + soff1] = (ACC)[1];                         \
    base[(size_t)(O0) * BATCH + soff2] = (ACC)[2];                         \
    base[(size_t)(O0) * BATCH + soff3] = (ACC)[3];                         \
  }
  ST(A0, 0); ST(A1, 16); ST(A2, 32); ST(A3, 48);
  ST(A4, 64); ST(A5, 80); ST(A6, 84);
#undef ST
}

// ---------------------------------------------------------------------------
// K2: BN stats per (t,o) row: mu, rstd. One wave per row.
// ---------------------------------------------------------------------------
__global__ __launch_bounds__(256) void k2_bnstats(const double* __restrict__ I1T,
                                                  double* __restrict__ mu,
                                                  double* __restrict__ rstd) {
  const int r    = blockIdx.x * 4 + (threadIdx.x >> 6);
  const int lane = threadIdx.x & 63;
  const double2* row2 = reinterpret_cast<const double2*>(I1T + (size_t)r * BATCH) + lane * 4;
  double v[8];
#pragma unroll
  for (int u = 0; u < 4; ++u) {
    double2 p = row2[u];
    v[2 * u] = p.x; v[2 * u + 1] = p.y;
  }
  double s = 0.0;
#pragma unroll
  for (int u = 0; u < 8; ++u) s += v[u];
#pragma unroll
  for (int m = 32; m >= 1; m >>= 1) s += __shfl_xor(s, m, 64);
  const double mean = s / 512.0;
  double q = 0.0;
#pragma unroll
  for (int u = 0; u < 8; ++u) { double d = v[u] - mean; q += d * d; }
#pragma unroll
  for (int m = 32; m >= 1; m >>= 1) q += __shfl_xor(q, m, 64);
  if (lane == 0) {
    mu[r]   = mean;
    rstd[r] = 1.0 / sqrt(q / 512.0 + 1e-5);
  }
}

// ---------------------------------------------------------------------------
// K3: layer-1 LIF scan. Block = o, thread = b.
// ---------------------------------------------------------------------------
__global__ __launch_bounds__(512) void k3_lif1(const double* __restrict__ I1T,
                                               const double* __restrict__ mu,
                                               const double* __restrict__ rstd,
                                               const float* __restrict__ scale,
                                               const float* __restrict__ bias,
                                               float* __restrict__ z1T) {
  const int o = blockIdx.x;
  const int b = threadIdx.x;
  const double sc = (double)scale[o], bs = (double)bias[o];
  double v = 0.0;
  for (int tc = 0; tc < T_STEPS; tc += 10) {
    double x[10], muv[10], rsv[10];
#pragma unroll
    for (int u = 0; u < 10; ++u) {
      const int t = tc + u;
      x[u]   = I1T[((size_t)t * O1 + o) * BATCH + b];
      muv[u] = mu[t * O1 + o];
      rsv[u] = rstd[t * O1 + o];
    }
#pragma unroll
    for (int u = 0; u < 10; ++u) {
      const double i = ((x[u] - muv[u]) * rsv[u]) * sc + bs;
      v = 0.95 * v + i;
      const bool z = (v > 1.0);
      z1T[((size_t)(tc + u) * O1 + o) * BATCH + b] = z ? 1.0f : 0.0f;
      if (z) v = 0.0;
    }
  }
}

// ---------------------------------------------------------------------------
// K4: I2[t][j][b] = sum_o z1T[t][o][b] * W2[o][j].
// ---------------------------------------------------------------------------
__global__ __launch_bounds__(512) void k4_proj2(const float* __restrict__ z1T,
                                                const float* __restrict__ W2,
                                                double* __restrict__ I2) {
  __shared__ double W2_lds[O1 * O2];
  const int t = blockIdx.x;
  const int b = threadIdx.x;
  for (int i = threadIdx.x; i < O1 * O2; i += 512) W2_lds[i] = (double)W2[i];
  __syncthreads();
  double acc[O2];
#pragma unroll
  for (int j = 0; j < O2; ++j) acc[j] = 0.0;
  for (int o = 0; o < O1; ++o) {
    const double z = (double)z1T[((size_t)t * O1 + o) * BATCH + b];
#pragma unroll
    for (int j = 0; j < O2; ++j) acc[j] += z * W2_lds[o * O2 + j];
  }
#pragma unroll
  for (int j = 0; j < O2; ++j)
    I2[((size_t)t * O2 + j) * BATCH + b] = acc[j];
}

// ---------------------------------------------------------------------------
// K5: layer-2 LIF scan + time-mean.
// ---------------------------------------------------------------------------
__global__ __launch_bounds__(512) void k5_lif2(const double* __restrict__ I2,
                                               float* __restrict__ out) {
  const int j = blockIdx.x;
  const int b = threadIdx.x;
  double v = 0.0;
  int cnt = 0;
  for (int tc = 0; tc < T_STEPS; tc += 10) {
    double x[10];
#pragma unroll
    for (int u = 0; u < 10; ++u)
      x[u] = I2[((size_t)(tc + u) * O2 + j) * BATCH + b];
#pragma unroll
    for (int u = 0; u < 10; ++u) {
      v = 0.95 * v + x[u];
      if (v > 1.0) { ++cnt; v = 0.0; }
    }
  }
  out[b * O2 + j] = (float)((double)cnt / 100.0);
}

// ---------------------------------------------------------------------------
extern "C" void kernel_launch(void* const* d_in, const int* in_sizes, int n_in,
                              void* d_out, int out_size, void* d_ws, size_t ws_size,
                              hipStream_t stream) {
  const float* in    = (const float*)d_in[0];
  const float* W1    = (const float*)d_in[2];
  const float* scale = (const float*)d_in[3];
  const float* bias  = (const float*)d_in[4];
  const float* W2    = (const float*)d_in[5];
  float* out = (float*)d_out;

  char* ws = (char*)d_ws;
  size_t off = 0;
  double* I1T  = (double*)(ws + off); off += (size_t)T_STEPS * O1 * BATCH * sizeof(double);
  double* mu   = (double*)(ws + off); off += (size_t)T_STEPS * O1 * sizeof(double);
  double* rstd = (double*)(ws + off); off += (size_t)T_STEPS * O1 * sizeof(double);
  float*  z1T  = (float*)(ws + off);  off += (size_t)T_STEPS * O1 * BATCH * sizeof(float);
  double* I2   = (double*)(ws + off); off += (size_t)T_STEPS * O2 * BATCH * sizeof(double);

  k1_mfma   <<<dim3(BATCH / 64, T_STEPS), 256, 0, stream>>>(in, W1, I1T);
  k2_bnstats<<<dim3(T_STEPS * O1 / 4), 256, 0, stream>>>(I1T, mu, rstd);
  k3_lif1   <<<dim3(O1), 512, 0, stream>>>(I1T, mu, rstd, scale, bias, z1T);
  k4_proj2  <<<dim3(T_STEPS), 512, 0, stream>>>(z1T, W2, I2);
  k5_lif2   <<<dim3(O2), 512, 0, stream>>>(I2, out);
}